// Round 1
// baseline (356.547 us; speedup 1.0000x reference)
//
#include <hip/hip_runtime.h>

#define B_ 4
#define N_ 16384
#define C_ 128
#define M_ 1024
#define K_ 32
#define NTOT (B_*M_*K_)   /* 131072 */
#define RAD2 0.16f
#define EPS_ 1e-5f

typedef unsigned short ushort_t;
typedef __bf16 bf16x8 __attribute__((ext_vector_type(8)));
typedef float f32x4 __attribute__((ext_vector_type(4)));

__device__ __forceinline__ float b2f(ushort_t u){
  unsigned int x = ((unsigned int)u) << 16;
  return __builtin_bit_cast(float, x);
}
__device__ __forceinline__ ushort_t f2b(float f){
  unsigned int u = __builtin_bit_cast(unsigned int, f);
  unsigned int r = (u + 0x7FFFu + ((u >> 16) & 1u)) >> 16;
  return (ushort_t)r;
}

// ---------------- ball query (1 wave per query, ordered-slot ballot) --------
__global__ __launch_bounds__(64) void ball_query_k(
    const float* __restrict__ xyz, const int* __restrict__ indices,
    float* __restrict__ new_xyz, int* __restrict__ idx)
{
  int g = blockIdx.x;                 // 0..4095
  int b = g >> 10, m = g & 1023;
  int lane = threadIdx.x;
  int qi = indices[b*M_ + m];
  const float* pb = xyz + (size_t)b*N_*3;
  float qx = pb[qi*3+0], qy = pb[qi*3+1], qz = pb[qi*3+2];
  if (lane < 3) new_xyz[g*3 + lane] = pb[qi*3 + lane];
  int cnt = 0, firstIdx = 0;
  int* op = idx + g*K_;
  for (int c0 = 0; c0 < N_; c0 += 64){
    int j = c0 + lane;
    float dx = pb[j*3+0]-qx, dy = pb[j*3+1]-qy, dz = pb[j*3+2]-qz;
    bool within = (dx*dx + dy*dy + dz*dz) < RAD2;
    unsigned long long mask = __ballot(within);
    if (cnt == 0 && mask) firstIdx = c0 + __builtin_ctzll(mask);
    if (within){
      int slot = cnt + __popcll(mask & ((1ull << lane) - 1ull));
      if (slot < K_) op[slot] = j;
    }
    cnt += __popcll(mask);
    if (cnt >= K_) break;
  }
  if (cnt < K_){
    for (int s = cnt + lane; s < K_; s += 64) op[s] = firstIdx;
  }
}

// ---------------- features (B,C,N) f32 -> (B,N,C) bf16 ----------------------
__global__ __launch_bounds__(256) void transpose_feat_k(
    const float* __restrict__ feat, ushort_t* __restrict__ ftr_t)
{
  __shared__ float T[32][133];
  int bi = blockIdx.x;
  int b = bi >> 9, ntile = bi & 511;
  int n0 = ntile * 32;
  int t = threadIdx.x;
  int nl = t & 31;
  #pragma unroll
  for (int ci = 0; ci < 16; ci++){
    int c = ci*8 + (t >> 5);
    T[nl][c] = feat[((size_t)b*C_ + c)*N_ + n0 + nl];
  }
  __syncthreads();
  #pragma unroll
  for (int ii = 0; ii < 2; ii++){
    int v = ii*256 + t;
    int n2 = v >> 4, seg = v & 15;
    union { ushort_t u[8]; uint4 q; } pk;
    #pragma unroll
    for (int j = 0; j < 8; j++) pk.u[j] = f2b(T[n2][seg*8 + j]);
    *(uint4*)(ftr_t + ((size_t)b*N_ + n0 + n2)*C_ + seg*8) = pk.q;
  }
}

// ---------------- weights f32 -> padded bf16 (W1 reordered: feat|xyz|0) -----
__global__ __launch_bounds__(256) void prep_w_k(
    const float* __restrict__ w1, const float* __restrict__ w2, const float* __restrict__ w3,
    ushort_t* __restrict__ W1b, ushort_t* __restrict__ W2b, ushort_t* __restrict__ W3b)
{
  const int T1 = 128*160, T2 = 128*136, T3 = 256*136;
  for (int e = blockIdx.x*256 + threadIdx.x; e < T1+T2+T3; e += gridDim.x*256){
    if (e < T1){
      int o = e / 160, c = e % 160;
      float v = 0.f;
      if (c < 128) v = w1[o*131 + 3 + c];
      else if (c < 131) v = w1[o*131 + (c - 128)];
      W1b[e] = f2b(v);
    } else if (e < T1+T2){
      int e2 = e - T1; int o = e2 / 136, c = e2 % 136;
      W2b[e2] = f2b(c < 128 ? w2[o*128 + c] : 0.f);
    } else {
      int e3 = e - T1 - T2; int o = e3 / 136, c = e3 % 136;
      W3b[e3] = f2b(c < 128 ? w3[o*128 + c] : 0.f);
    }
  }
}

// ---------------- MFMA GEMM for one 32-row group (1 wave) -------------------
// A: A[m=lane&15][k=quad*8+j] ; B: B[k=quad*8+j][n=lane&15] ; D: col=lane&15,row=quad*4+reg
template<int KT, int NT, int COUT, int XSTR, int WSTR>
__device__ __forceinline__ void mfma_group(
    const ushort_t* Xs_grp, const ushort_t* __restrict__ Wb,
    const float* __restrict__ bias, ushort_t* __restrict__ Y, int g_global,
    float* lds_sum, float* lds_sq)
{
  int lane = threadIdx.x & 63;
  int quad = lane >> 4, l15 = lane & 15;
  bf16x8 af[2][KT];
  #pragma unroll
  for (int mt = 0; mt < 2; mt++)
    #pragma unroll
    for (int kt = 0; kt < KT; kt++)
      af[mt][kt] = *(const bf16x8*)(Xs_grp + (mt*16 + l15)*XSTR + kt*32 + quad*8);
  ushort_t* Yg = Y + (size_t)g_global*K_*COUT;
  #pragma unroll
  for (int nt = 0; nt < NT; nt++){
    f32x4 acc0 = {0.f,0.f,0.f,0.f}, acc1 = {0.f,0.f,0.f,0.f};
    const ushort_t* wp = Wb + (nt*16 + l15)*WSTR + quad*8;
    #pragma unroll
    for (int kt = 0; kt < KT; kt++){
      bf16x8 bf = *(const bf16x8*)(wp + kt*32);
      acc0 = __builtin_amdgcn_mfma_f32_16x16x32_bf16(af[0][kt], bf, acc0, 0, 0, 0);
      acc1 = __builtin_amdgcn_mfma_f32_16x16x32_bf16(af[1][kt], bf, acc1, 0, 0, 0);
    }
    int o = nt*16 + l15;
    float bs = bias[o];
    float s = 0.f, s2 = 0.f;
    #pragma unroll
    for (int mt = 0; mt < 2; mt++){
      f32x4 a = mt ? acc1 : acc0;
      #pragma unroll
      for (int r = 0; r < 4; r++){
        float v = a[r] + bs;
        int rloc = mt*16 + quad*4 + r;
        Yg[rloc*COUT + o] = f2b(v);
        s += v; s2 += v*v;
      }
    }
    // reduce the 4 quads holding the same o before touching LDS
    s  += __shfl_xor(s, 16);  s  += __shfl_xor(s, 32);
    s2 += __shfl_xor(s2, 16); s2 += __shfl_xor(s2, 32);
    if (quad == 0){ atomicAdd(&lds_sum[o], s); atomicAdd(&lds_sq[o], s2); }
  }
}

// ---------------- conv1: gather (xyzdiff | feat) -> GEMM --------------------
__global__ __launch_bounds__(256, 2) void conv1_k(
    const float* __restrict__ xyz, const ushort_t* __restrict__ ftr_t,
    const int* __restrict__ idx, const float* __restrict__ new_xyz,
    const ushort_t* __restrict__ W1b, const float* __restrict__ b1,
    ushort_t* __restrict__ Y1, float* __restrict__ sumO, float* __restrict__ sqO)
{
  __shared__ alignas(16) ushort_t Xs[4*32*168];
  __shared__ int idxs[128];
  __shared__ float qs[4][3];
  __shared__ float lsum[128], lsq[128];
  int t = threadIdx.x;
  int g0 = blockIdx.x * 4;
  if (t < 128){ idxs[t] = idx[g0*K_ + t]; lsum[t] = 0.f; lsq[t] = 0.f; }
  if (t < 12) qs[t/3][t%3] = new_xyz[(g0 + t/3)*3 + t%3];
  __syncthreads();
  #pragma unroll
  for (int i = 0; i < 8; i++){           // gather feat rows (contiguous 256B)
    int v = i*256 + t;
    int row = v >> 4, seg = v & 15;
    int gl = row >> 5, r = row & 31;
    int n = idxs[row];
    int b = (g0 + gl) >> 10;
    uint4 q = *(const uint4*)(ftr_t + ((size_t)b*N_ + n)*C_ + seg*8);
    *(uint4*)(Xs + gl*(32*168) + r*168 + seg*8) = q;
  }
  if (t < 128){                          // xyz diff at cols 128..130, zero pad
    int gl = t >> 5, r = t & 31;
    int n = idxs[t];
    int b = (g0 + gl) >> 10;
    ushort_t* xr = Xs + gl*(32*168) + r*168;
    const float* pp = xyz + ((size_t)b*N_ + n)*3;
    #pragma unroll
    for (int j = 0; j < 3; j++) xr[128 + j] = f2b(pp[j] - qs[gl][j]);
    for (int c = 131; c < 168; c++) xr[c] = 0;
  }
  __syncthreads();
  int wv = t >> 6;
  mfma_group<5, 8, 128, 168, 160>(Xs + wv*(32*168), W1b, b1, Y1, g0 + wv, lsum, lsq);
  __syncthreads();
  if (t < 128){ atomicAdd(&sumO[t], lsum[t]); atomicAdd(&sqO[t], lsq[t]); }
}

// ---------------- conv2/3: BN(prev)+relu folded into staging ----------------
template<int COUT>
__global__ __launch_bounds__(256, 2) void convN_k(
    const ushort_t* __restrict__ Yin, const ushort_t* __restrict__ Wb,
    const float* __restrict__ bias, const float* __restrict__ g_bn,
    const float* __restrict__ beta_bn, const float* __restrict__ sumI,
    const float* __restrict__ sqI, ushort_t* __restrict__ Yout,
    float* __restrict__ sumO, float* __restrict__ sqO)
{
  __shared__ alignas(16) ushort_t Xs[4*32*136];
  __shared__ float abn[128], dbn[128];
  __shared__ float lsum[COUT], lsq[COUT];
  int t = threadIdx.x;
  int g0 = blockIdx.x * 4;
  if (t < 128){
    float mu  = sumI[t] * (1.f/NTOT);
    float var = sqI[t]  * (1.f/NTOT) - mu*mu;
    float a = g_bn[t] * rsqrtf(var + EPS_);
    abn[t] = a;
    dbn[t] = beta_bn[t] - a*mu;
  }
  if (t < COUT){ lsum[t] = 0.f; lsq[t] = 0.f; }
  __syncthreads();
  const ushort_t* src = Yin + (size_t)g0*K_*128;
  #pragma unroll
  for (int i = 0; i < 8; i++){
    int v = i*256 + t;
    int row = v >> 4, seg = v & 15;
    int c0 = seg*8;
    union { ushort_t u[8]; uint4 q; } in, outp;
    in.q = *(const uint4*)(src + row*128 + c0);
    #pragma unroll
    for (int j = 0; j < 8; j++){
      float x = b2f(in.u[j]);
      float y = abn[c0+j]*x + dbn[c0+j];
      outp.u[j] = f2b(fmaxf(y, 0.f));
    }
    int gl = row >> 5, r = row & 31;
    *(uint4*)(Xs + gl*(32*136) + r*136 + c0) = outp.q;
  }
  if (t < 128){
    int gl = t >> 5, r = t & 31;
    *(uint4*)(Xs + gl*(32*136) + r*136 + 128) = make_uint4(0,0,0,0);
  }
  __syncthreads();
  int wv = t >> 6;
  mfma_group<4, COUT/16, COUT, 136, 136>(Xs + wv*(32*136), Wb, bias, Yout, g0 + wv, lsum, lsq);
  __syncthreads();
  if (t < COUT){ atomicAdd(&sumO[t], lsum[t]); atomicAdd(&sqO[t], lsq[t]); }
}

// ---------------- BN3 + relu + max over K, transposed store -----------------
__global__ __launch_bounds__(256) void finalize_k(
    const ushort_t* __restrict__ Y3, const float* __restrict__ g3,
    const float* __restrict__ beta3, const float* __restrict__ sum3,
    const float* __restrict__ sq3, float* __restrict__ out)
{
  __shared__ float T[16][257];
  __shared__ float abn[256], dbn[256];
  int t = threadIdx.x;
  int b = blockIdx.x >> 6;
  int m0 = (blockIdx.x & 63) << 4;
  {
    float mu  = sum3[t] * (1.f/NTOT);
    float var = sq3[t]  * (1.f/NTOT) - mu*mu;
    float a = g3[t] * rsqrtf(var + EPS_);
    abn[t] = a; dbn[t] = beta3[t] - a*mu;
  }
  __syncthreads();
  float a = abn[t], d = dbn[t];
  for (int mm = 0; mm < 16; mm++){
    size_t base = ((size_t)(b*M_ + m0 + mm) * K_) * 256 + t;
    float mx = -1e30f;
    #pragma unroll
    for (int r = 0; r < 32; r++){
      float y = b2f(Y3[base + (size_t)r*256]);
      mx = fmaxf(mx, a*y + d);
    }
    T[mm][t] = fmaxf(mx, 0.f);
  }
  __syncthreads();
  int o0 = t >> 4, ml = t & 15;
  #pragma unroll
  for (int oi = 0; oi < 16; oi++){
    int o = oi*16 + o0;
    out[(size_t)b*256*M_ + (size_t)o*M_ + m0 + ml] = T[ml][o];
  }
}

extern "C" void kernel_launch(void* const* d_in, const int* in_sizes, int n_in,
                              void* d_out, int out_size, void* d_ws, size_t ws_size,
                              hipStream_t stream)
{
  (void)in_sizes; (void)n_in; (void)out_size; (void)ws_size;
  const float* xyz  = (const float*)d_in[0];
  const float* feat = (const float*)d_in[1];
  const int*   inds = (const int*)d_in[2];
  const float* w1 = (const float*)d_in[3];
  const float* b1 = (const float*)d_in[4];
  const float* g1 = (const float*)d_in[5];
  const float* be1= (const float*)d_in[6];
  const float* w2 = (const float*)d_in[7];
  const float* b2 = (const float*)d_in[8];
  const float* g2 = (const float*)d_in[9];
  const float* be2= (const float*)d_in[10];
  const float* w3 = (const float*)d_in[11];
  const float* b3 = (const float*)d_in[12];
  const float* g3 = (const float*)d_in[13];
  const float* be3= (const float*)d_in[14];

  char* ws = (char*)d_ws;
  float* stats = (float*)ws;                  // 6*256 f32, zeroed each call
  float* s1sum = stats + 0*256;  float* s1sq = stats + 1*256;
  float* s2sum = stats + 2*256;  float* s2sq = stats + 3*256;
  float* s3sum = stats + 4*256;  float* s3sq = stats + 5*256;
  size_t off = 6*256*sizeof(float);
  int* idx = (int*)(ws + off);                off += (size_t)B_*M_*K_*4;
  ushort_t* ftr_t = (ushort_t*)(ws + off);    off += (size_t)B_*N_*C_*2;
  ushort_t* W1b = (ushort_t*)(ws + off);      off += 128*160*2;
  ushort_t* W2b = (ushort_t*)(ws + off);      off += 128*136*2;
  ushort_t* W3b = (ushort_t*)(ws + off);      off += 256*136*2;
  ushort_t* Y1 = (ushort_t*)(ws + off);       off += (size_t)NTOT*128*2;
  ushort_t* Y2 = (ushort_t*)(ws + off);       off += (size_t)NTOT*128*2;
  ushort_t* Y3 = (ushort_t*)(ws + off);       off += (size_t)NTOT*256*2;
  // total ws use ~152 MB

  float* new_xyz  = (float*)d_out;
  float* out_feat = (float*)d_out + (size_t)B_*M_*3;

  hipMemsetAsync(stats, 0, 6*256*sizeof(float), stream);
  prep_w_k<<<284, 256, 0, stream>>>(w1, w2, w3, W1b, W2b, W3b);
  transpose_feat_k<<<2048, 256, 0, stream>>>(feat, ftr_t);
  ball_query_k<<<4096, 64, 0, stream>>>(xyz, inds, new_xyz, idx);
  conv1_k<<<1024, 256, 0, stream>>>(xyz, ftr_t, idx, new_xyz, W1b, b1, Y1, s1sum, s1sq);
  convN_k<128><<<1024, 256, 0, stream>>>(Y1, W2b, b2, g1, be1, s1sum, s1sq, Y2, s2sum, s2sq);
  convN_k<256><<<1024, 256, 0, stream>>>(Y2, W3b, b3, g2, be2, s2sum, s2sq, Y3, s3sum, s3sq);
  finalize_k<<<256, 256, 0, stream>>>(Y3, g3, be3, s3sum, s3sq, out_feat);
}

// Round 2
// 299.578 us; speedup vs baseline: 1.1902x; 1.1902x over previous
//
#include <hip/hip_runtime.h>

#define B_ 4
#define N_ 16384
#define C_ 128
#define M_ 1024
#define K_ 32
#define NTOT (B_*M_*K_)   /* 131072 */
#define RAD2 0.16f
#define EPS_ 1e-5f

typedef unsigned short ushort_t;
typedef __bf16 bf16x8 __attribute__((ext_vector_type(8)));
typedef float f32x4 __attribute__((ext_vector_type(4)));

__device__ __forceinline__ float b2f(ushort_t u){
  unsigned int x = ((unsigned int)u) << 16;
  return __builtin_bit_cast(float, x);
}
__device__ __forceinline__ ushort_t f2b(float f){
  unsigned int u = __builtin_bit_cast(unsigned int, f);
  unsigned int r = (u + 0x7FFFu + ((u >> 16) & 1u)) >> 16;
  return (ushort_t)r;
}

// ---------------- ball query: 4 queries/block, LDS-staged double-buffered ---
// Chunk = 512 points (6 KB). Global loads for chunk k+1 issue before the
// ballot rounds of chunk k; LDS write + one __syncthreads_and per chunk.
// 8 ds_reads issued up-front per chunk -> serial chain is ~32 steps, not 256.
__global__ __launch_bounds__(256) void ball_query_k(
    const float* __restrict__ xyz, const int* __restrict__ indices,
    float* __restrict__ new_xyz, int* __restrict__ idx)
{
  __shared__ float pts[2][512*3];
  int t = threadIdx.x;
  int wv = t >> 6, lane = t & 63;
  int g = blockIdx.x*4 + wv;          // query id (0..4095); same batch per block
  int b = g >> 10;
  const float* pb = xyz + (size_t)b*N_*3;
  int qi = indices[g];
  float qx = pb[qi*3+0], qy = pb[qi*3+1], qz = pb[qi*3+2];
  if (lane < 3) new_xyz[g*3 + lane] = pb[qi*3 + lane];

  // stage chunk 0 (each thread moves 24 B = 3 float2)
  float2 st0, st1, st2;
  {
    const float2* src = (const float2*)pb + t*3;
    st0 = src[0]; st1 = src[1]; st2 = src[2];
    float2* dst = (float2*)(&pts[0][0]) + t*3;
    dst[0] = st0; dst[1] = st1; dst[2] = st2;
  }
  __syncthreads();

  int cnt = 0, firstIdx = 0;
  int* op = idx + g*K_;
  for (int chunk = 0; chunk < 32; chunk++){
    int cur = chunk & 1;
    bool have_next = (chunk + 1 < 32);
    if (have_next){                    // issue next chunk's global loads now
      const float2* src = (const float2*)(pb + (chunk+1)*512*3) + t*3;
      st0 = src[0]; st1 = src[1]; st2 = src[2];
    }
    if (cnt < K_){
      int base = chunk*512;
      float px[8], py[8], pz[8];
      #pragma unroll
      for (int r = 0; r < 8; r++){     // all 8 LDS reads in flight
        const float* p = &pts[cur][(r*64 + lane)*3];
        px[r] = p[0]; py[r] = p[1]; pz[r] = p[2];
      }
      #pragma unroll
      for (int r = 0; r < 8; r++){
        float dx = px[r]-qx, dy = py[r]-qy, dz = pz[r]-qz;
        bool within = (dx*dx + dy*dy + dz*dz) < RAD2;
        unsigned long long mask = __ballot(within);
        if (cnt == 0 && mask) firstIdx = base + r*64 + __builtin_ctzll(mask);
        if (within){
          int slot = cnt + __popcll(mask & ((1ull << lane) - 1ull));
          if (slot < K_) op[slot] = base + r*64 + lane;
        }
        cnt += __popcll(mask);
      }
    }
    if (have_next){                    // write-behind into the other buffer
      float2* dst = (float2*)(&pts[1-cur][0]) + t*3;
      dst[0] = st0; dst[1] = st1; dst[2] = st2;
    }
    if (__syncthreads_and(cnt >= K_)) break;   // uniform, race-free exit
  }
  if (cnt < K_){
    for (int s = cnt + lane; s < K_; s += 64) op[s] = firstIdx;
  }
}

// ---------------- features (B,C,N) f32 -> (B,N,C) bf16 ----------------------
__global__ __launch_bounds__(256) void transpose_feat_k(
    const float* __restrict__ feat, ushort_t* __restrict__ ftr_t)
{
  __shared__ float T[32][133];
  int bi = blockIdx.x;
  int b = bi >> 9, ntile = bi & 511;
  int n0 = ntile * 32;
  int t = threadIdx.x;
  int nl = t & 31;
  #pragma unroll
  for (int ci = 0; ci < 16; ci++){
    int c = ci*8 + (t >> 5);
    T[nl][c] = feat[((size_t)b*C_ + c)*N_ + n0 + nl];
  }
  __syncthreads();
  #pragma unroll
  for (int ii = 0; ii < 2; ii++){
    int v = ii*256 + t;
    int n2 = v >> 4, seg = v & 15;
    union { ushort_t u[8]; uint4 q; } pk;
    #pragma unroll
    for (int j = 0; j < 8; j++) pk.u[j] = f2b(T[n2][seg*8 + j]);
    *(uint4*)(ftr_t + ((size_t)b*N_ + n0 + n2)*C_ + seg*8) = pk.q;
  }
}

// ---------------- weights f32 -> padded bf16 (W1 reordered: feat|xyz|0) -----
__global__ __launch_bounds__(256) void prep_w_k(
    const float* __restrict__ w1, const float* __restrict__ w2, const float* __restrict__ w3,
    ushort_t* __restrict__ W1b, ushort_t* __restrict__ W2b, ushort_t* __restrict__ W3b)
{
  const int T1 = 128*160, T2 = 128*136, T3 = 256*136;
  for (int e = blockIdx.x*256 + threadIdx.x; e < T1+T2+T3; e += gridDim.x*256){
    if (e < T1){
      int o = e / 160, c = e % 160;
      float v = 0.f;
      if (c < 128) v = w1[o*131 + 3 + c];
      else if (c < 131) v = w1[o*131 + (c - 128)];
      W1b[e] = f2b(v);
    } else if (e < T1+T2){
      int e2 = e - T1; int o = e2 / 136, c = e2 % 136;
      W2b[e2] = f2b(c < 128 ? w2[o*128 + c] : 0.f);
    } else {
      int e3 = e - T1 - T2; int o = e3 / 136, c = e3 % 136;
      W3b[e3] = f2b(c < 128 ? w3[o*128 + c] : 0.f);
    }
  }
}

// ---------------- MFMA GEMM for one 32-row group (1 wave) -------------------
// A: A[m=lane&15][k=quad*8+j] ; B: B[k=quad*8+j][n=lane&15] ; D: col=lane&15,row=quad*4+reg
template<int KT, int NT, int COUT, int XSTR, int WSTR>
__device__ __forceinline__ void mfma_group(
    const ushort_t* Xs_grp, const ushort_t* __restrict__ Wb,
    const float* __restrict__ bias, ushort_t* __restrict__ Y, int g_global,
    float* lds_sum, float* lds_sq)
{
  int lane = threadIdx.x & 63;
  int quad = lane >> 4, l15 = lane & 15;
  bf16x8 af[2][KT];
  #pragma unroll
  for (int mt = 0; mt < 2; mt++)
    #pragma unroll
    for (int kt = 0; kt < KT; kt++)
      af[mt][kt] = *(const bf16x8*)(Xs_grp + (mt*16 + l15)*XSTR + kt*32 + quad*8);
  ushort_t* Yg = Y + (size_t)g_global*K_*COUT;
  #pragma unroll
  for (int nt = 0; nt < NT; nt++){
    f32x4 acc0 = {0.f,0.f,0.f,0.f}, acc1 = {0.f,0.f,0.f,0.f};
    const ushort_t* wp = Wb + (nt*16 + l15)*WSTR + quad*8;
    #pragma unroll
    for (int kt = 0; kt < KT; kt++){
      bf16x8 bf = *(const bf16x8*)(wp + kt*32);
      acc0 = __builtin_amdgcn_mfma_f32_16x16x32_bf16(af[0][kt], bf, acc0, 0, 0, 0);
      acc1 = __builtin_amdgcn_mfma_f32_16x16x32_bf16(af[1][kt], bf, acc1, 0, 0, 0);
    }
    int o = nt*16 + l15;
    float bs = bias[o];
    float s = 0.f, s2 = 0.f;
    #pragma unroll
    for (int mt = 0; mt < 2; mt++){
      f32x4 a = mt ? acc1 : acc0;
      #pragma unroll
      for (int r = 0; r < 4; r++){
        float v = a[r] + bs;
        int rloc = mt*16 + quad*4 + r;
        Yg[rloc*COUT + o] = f2b(v);
        s += v; s2 += v*v;
      }
    }
    // reduce the 4 quads holding the same o before touching LDS
    s  += __shfl_xor(s, 16);  s  += __shfl_xor(s, 32);
    s2 += __shfl_xor(s2, 16); s2 += __shfl_xor(s2, 32);
    if (quad == 0){ atomicAdd(&lds_sum[o], s); atomicAdd(&lds_sq[o], s2); }
  }
}

// ---------------- conv1: gather (xyzdiff | feat) -> GEMM --------------------
__global__ __launch_bounds__(256, 2) void conv1_k(
    const float* __restrict__ xyz, const ushort_t* __restrict__ ftr_t,
    const int* __restrict__ idx, const float* __restrict__ new_xyz,
    const ushort_t* __restrict__ W1b, const float* __restrict__ b1,
    ushort_t* __restrict__ Y1, float* __restrict__ sumO, float* __restrict__ sqO)
{
  __shared__ alignas(16) ushort_t Xs[4*32*168];
  __shared__ int idxs[128];
  __shared__ float qs[4][3];
  __shared__ float lsum[128], lsq[128];
  int t = threadIdx.x;
  int g0 = blockIdx.x * 4;
  if (t < 128){ idxs[t] = idx[g0*K_ + t]; lsum[t] = 0.f; lsq[t] = 0.f; }
  if (t < 12) qs[t/3][t%3] = new_xyz[(g0 + t/3)*3 + t%3];
  __syncthreads();
  #pragma unroll
  for (int i = 0; i < 8; i++){           // gather feat rows (contiguous 256B)
    int v = i*256 + t;
    int row = v >> 4, seg = v & 15;
    int gl = row >> 5, r = row & 31;
    int n = idxs[row];
    int b = (g0 + gl) >> 10;
    uint4 q = *(const uint4*)(ftr_t + ((size_t)b*N_ + n)*C_ + seg*8);
    *(uint4*)(Xs + gl*(32*168) + r*168 + seg*8) = q;
  }
  if (t < 128){                          // xyz diff at cols 128..130, zero pad
    int gl = t >> 5, r = t & 31;
    int n = idxs[t];
    int b = (g0 + gl) >> 10;
    ushort_t* xr = Xs + gl*(32*168) + r*168;
    const float* pp = xyz + ((size_t)b*N_ + n)*3;
    #pragma unroll
    for (int j = 0; j < 3; j++) xr[128 + j] = f2b(pp[j] - qs[gl][j]);
    for (int c = 131; c < 168; c++) xr[c] = 0;
  }
  __syncthreads();
  int wv = t >> 6;
  mfma_group<5, 8, 128, 168, 160>(Xs + wv*(32*168), W1b, b1, Y1, g0 + wv, lsum, lsq);
  __syncthreads();
  if (t < 128){ atomicAdd(&sumO[t], lsum[t]); atomicAdd(&sqO[t], lsq[t]); }
}

// ---------------- conv2/3: BN(prev)+relu folded into staging ----------------
template<int COUT>
__global__ __launch_bounds__(256, 2) void convN_k(
    const ushort_t* __restrict__ Yin, const ushort_t* __restrict__ Wb,
    const float* __restrict__ bias, const float* __restrict__ g_bn,
    const float* __restrict__ beta_bn, const float* __restrict__ sumI,
    const float* __restrict__ sqI, ushort_t* __restrict__ Yout,
    float* __restrict__ sumO, float* __restrict__ sqO)
{
  __shared__ alignas(16) ushort_t Xs[4*32*136];
  __shared__ float abn[128], dbn[128];
  __shared__ float lsum[COUT], lsq[COUT];
  int t = threadIdx.x;
  int g0 = blockIdx.x * 4;
  if (t < 128){
    float mu  = sumI[t] * (1.f/NTOT);
    float var = sqI[t]  * (1.f/NTOT) - mu*mu;
    float a = g_bn[t] * rsqrtf(var + EPS_);
    abn[t] = a;
    dbn[t] = beta_bn[t] - a*mu;
  }
  if (t < COUT){ lsum[t] = 0.f; lsq[t] = 0.f; }
  __syncthreads();
  const ushort_t* src = Yin + (size_t)g0*K_*128;
  #pragma unroll
  for (int i = 0; i < 8; i++){
    int v = i*256 + t;
    int row = v >> 4, seg = v & 15;
    int c0 = seg*8;
    union { ushort_t u[8]; uint4 q; } in, outp;
    in.q = *(const uint4*)(src + row*128 + c0);
    #pragma unroll
    for (int j = 0; j < 8; j++){
      float x = b2f(in.u[j]);
      float y = abn[c0+j]*x + dbn[c0+j];
      outp.u[j] = f2b(fmaxf(y, 0.f));
    }
    int gl = row >> 5, r = row & 31;
    *(uint4*)(Xs + gl*(32*136) + r*136 + c0) = outp.q;
  }
  if (t < 128){
    int gl = t >> 5, r = t & 31;
    *(uint4*)(Xs + gl*(32*136) + r*136 + 128) = make_uint4(0,0,0,0);
  }
  __syncthreads();
  int wv = t >> 6;
  mfma_group<4, COUT/16, COUT, 136, 136>(Xs + wv*(32*136), Wb, bias, Yout, g0 + wv, lsum, lsq);
  __syncthreads();
  if (t < COUT){ atomicAdd(&sumO[t], lsum[t]); atomicAdd(&sqO[t], lsq[t]); }
}

// ---------------- BN3 + relu + max over K, transposed store -----------------
__global__ __launch_bounds__(256) void finalize_k(
    const ushort_t* __restrict__ Y3, const float* __restrict__ g3,
    const float* __restrict__ beta3, const float* __restrict__ sum3,
    const float* __restrict__ sq3, float* __restrict__ out)
{
  __shared__ float T[16][257];
  __shared__ float abn[256], dbn[256];
  int t = threadIdx.x;
  int b = blockIdx.x >> 6;
  int m0 = (blockIdx.x & 63) << 4;
  {
    float mu  = sum3[t] * (1.f/NTOT);
    float var = sq3[t]  * (1.f/NTOT) - mu*mu;
    float a = g3[t] * rsqrtf(var + EPS_);
    abn[t] = a; dbn[t] = beta3[t] - a*mu;
  }
  __syncthreads();
  float a = abn[t], d = dbn[t];
  for (int mm = 0; mm < 16; mm++){
    size_t base = ((size_t)(b*M_ + m0 + mm) * K_) * 256 + t;
    float mx = -1e30f;
    #pragma unroll
    for (int r = 0; r < 32; r++){
      float y = b2f(Y3[base + (size_t)r*256]);
      mx = fmaxf(mx, a*y + d);
    }
    T[mm][t] = fmaxf(mx, 0.f);
  }
  __syncthreads();
  int o0 = t >> 4, ml = t & 15;
  #pragma unroll
  for (int oi = 0; oi < 16; oi++){
    int o = oi*16 + o0;
    out[(size_t)b*256*M_ + (size_t)o*M_ + m0 + ml] = T[ml][o];
  }
}

extern "C" void kernel_launch(void* const* d_in, const int* in_sizes, int n_in,
                              void* d_out, int out_size, void* d_ws, size_t ws_size,
                              hipStream_t stream)
{
  (void)in_sizes; (void)n_in; (void)out_size; (void)ws_size;
  const float* xyz  = (const float*)d_in[0];
  const float* feat = (const float*)d_in[1];
  const int*   inds = (const int*)d_in[2];
  const float* w1 = (const float*)d_in[3];
  const float* b1 = (const float*)d_in[4];
  const float* g1 = (const float*)d_in[5];
  const float* be1= (const float*)d_in[6];
  const float* w2 = (const float*)d_in[7];
  const float* b2 = (const float*)d_in[8];
  const float* g2 = (const float*)d_in[9];
  const float* be2= (const float*)d_in[10];
  const float* w3 = (const float*)d_in[11];
  const float* b3 = (const float*)d_in[12];
  const float* g3 = (const float*)d_in[13];
  const float* be3= (const float*)d_in[14];

  char* ws = (char*)d_ws;
  float* stats = (float*)ws;                  // 6*256 f32, zeroed each call
  float* s1sum = stats + 0*256;  float* s1sq = stats + 1*256;
  float* s2sum = stats + 2*256;  float* s2sq = stats + 3*256;
  float* s3sum = stats + 4*256;  float* s3sq = stats + 5*256;
  size_t off = 6*256*sizeof(float);
  int* idx = (int*)(ws + off);                off += (size_t)B_*M_*K_*4;
  ushort_t* ftr_t = (ushort_t*)(ws + off);    off += (size_t)B_*N_*C_*2;
  ushort_t* W1b = (ushort_t*)(ws + off);      off += 128*160*2;
  ushort_t* W2b = (ushort_t*)(ws + off);      off += 128*136*2;
  ushort_t* W3b = (ushort_t*)(ws + off);      off += 256*136*2;
  ushort_t* Y1 = (ushort_t*)(ws + off);       off += (size_t)NTOT*128*2;
  ushort_t* Y2 = (ushort_t*)(ws + off);       off += (size_t)NTOT*128*2;
  ushort_t* Y3 = (ushort_t*)(ws + off);       off += (size_t)NTOT*256*2;
  // total ws use ~152 MB

  float* new_xyz  = (float*)d_out;
  float* out_feat = (float*)d_out + (size_t)B_*M_*3;

  hipMemsetAsync(stats, 0, 6*256*sizeof(float), stream);
  prep_w_k<<<284, 256, 0, stream>>>(w1, w2, w3, W1b, W2b, W3b);
  transpose_feat_k<<<2048, 256, 0, stream>>>(feat, ftr_t);
  ball_query_k<<<1024, 256, 0, stream>>>(xyz, inds, new_xyz, idx);
  conv1_k<<<1024, 256, 0, stream>>>(xyz, ftr_t, idx, new_xyz, W1b, b1, Y1, s1sum, s1sq);
  convN_k<128><<<1024, 256, 0, stream>>>(Y1, W2b, b2, g1, be1, s1sum, s1sq, Y2, s2sum, s2sq);
  convN_k<256><<<1024, 256, 0, stream>>>(Y2, W3b, b3, g2, be2, s2sum, s2sq, Y3, s3sum, s3sq);
  finalize_k<<<256, 256, 0, stream>>>(Y3, g3, be3, s3sum, s3sq, out_feat);
}

// Round 3
// 250.195 us; speedup vs baseline: 1.4251x; 1.1974x over previous
//
#include <hip/hip_runtime.h>

#define B_ 4
#define N_ 16384
#define C_ 128
#define M_ 1024
#define K_ 32
#define NTOT (B_*M_*K_)   /* 131072 */
#define RAD2 0.16f
#define EPS_ 1e-5f

typedef unsigned short ushort_t;
typedef __bf16 bf16x8 __attribute__((ext_vector_type(8)));
typedef float f32x4 __attribute__((ext_vector_type(4)));

__device__ __forceinline__ float b2f(ushort_t u){
  unsigned int x = ((unsigned int)u) << 16;
  return __builtin_bit_cast(float, x);
}
__device__ __forceinline__ ushort_t f2b(float f){
  unsigned int u = __builtin_bit_cast(unsigned int, f);
  unsigned int r = (u + 0x7FFFu + ((u >> 16) & 1u)) >> 16;
  return (ushort_t)r;
}

// ---------------- ball query: 4 queries/block, LDS-staged double-buffered ---
__global__ __launch_bounds__(256) void ball_query_k(
    const float* __restrict__ xyz, const int* __restrict__ indices,
    float* __restrict__ new_xyz, int* __restrict__ idx)
{
  __shared__ float pts[2][512*3];
  int t = threadIdx.x;
  int wv = t >> 6, lane = t & 63;
  int g = blockIdx.x*4 + wv;
  int b = g >> 10;
  const float* pb = xyz + (size_t)b*N_*3;
  int qi = indices[g];
  float qx = pb[qi*3+0], qy = pb[qi*3+1], qz = pb[qi*3+2];
  if (lane < 3) new_xyz[g*3 + lane] = pb[qi*3 + lane];

  float2 st0, st1, st2;
  {
    const float2* src = (const float2*)pb + t*3;
    st0 = src[0]; st1 = src[1]; st2 = src[2];
    float2* dst = (float2*)(&pts[0][0]) + t*3;
    dst[0] = st0; dst[1] = st1; dst[2] = st2;
  }
  __syncthreads();

  int cnt = 0, firstIdx = 0;
  int* op = idx + g*K_;
  for (int chunk = 0; chunk < 32; chunk++){
    int cur = chunk & 1;
    bool have_next = (chunk + 1 < 32);
    if (have_next){
      const float2* src = (const float2*)(pb + (chunk+1)*512*3) + t*3;
      st0 = src[0]; st1 = src[1]; st2 = src[2];
    }
    if (cnt < K_){
      int base = chunk*512;
      float px[8], py[8], pz[8];
      #pragma unroll
      for (int r = 0; r < 8; r++){
        const float* p = &pts[cur][(r*64 + lane)*3];
        px[r] = p[0]; py[r] = p[1]; pz[r] = p[2];
      }
      #pragma unroll
      for (int r = 0; r < 8; r++){
        float dx = px[r]-qx, dy = py[r]-qy, dz = pz[r]-qz;
        bool within = (dx*dx + dy*dy + dz*dz) < RAD2;
        unsigned long long mask = __ballot(within);
        if (cnt == 0 && mask) firstIdx = base + r*64 + __builtin_ctzll(mask);
        if (within){
          int slot = cnt + __popcll(mask & ((1ull << lane) - 1ull));
          if (slot < K_) op[slot] = base + r*64 + lane;
        }
        cnt += __popcll(mask);
      }
    }
    if (have_next){
      float2* dst = (float2*)(&pts[1-cur][0]) + t*3;
      dst[0] = st0; dst[1] = st1; dst[2] = st2;
    }
    if (__syncthreads_and(cnt >= K_)) break;
  }
  if (cnt < K_){
    for (int s = cnt + lane; s < K_; s += 64) op[s] = firstIdx;
  }
}

// ---------------- features (B,C,N) f32 -> (B,N,C) bf16 ----------------------
__global__ __launch_bounds__(256) void transpose_feat_k(
    const float* __restrict__ feat, ushort_t* __restrict__ ftr_t)
{
  __shared__ float T[32][133];
  int bi = blockIdx.x;
  int b = bi >> 9, ntile = bi & 511;
  int n0 = ntile * 32;
  int t = threadIdx.x;
  int nl = t & 31;
  #pragma unroll
  for (int ci = 0; ci < 16; ci++){
    int c = ci*8 + (t >> 5);
    T[nl][c] = feat[((size_t)b*C_ + c)*N_ + n0 + nl];
  }
  __syncthreads();
  #pragma unroll
  for (int ii = 0; ii < 2; ii++){
    int v = ii*256 + t;
    int n2 = v >> 4, seg = v & 15;
    union { ushort_t u[8]; uint4 q; } pk;
    #pragma unroll
    for (int j = 0; j < 8; j++) pk.u[j] = f2b(T[n2][seg*8 + j]);
    *(uint4*)(ftr_t + ((size_t)b*N_ + n0 + n2)*C_ + seg*8) = pk.q;
  }
}

// ---------------- weights f32 -> bf16 (W1 reordered: feat|xyz|0, stride 160) -
__global__ __launch_bounds__(256) void prep_w_k(
    const float* __restrict__ w1, const float* __restrict__ w2, const float* __restrict__ w3,
    ushort_t* __restrict__ W1b, ushort_t* __restrict__ W2b, ushort_t* __restrict__ W3b)
{
  const int T1 = 128*160, T2 = 128*128, T3 = 256*128;
  for (int e = blockIdx.x*256 + threadIdx.x; e < T1+T2+T3; e += gridDim.x*256){
    if (e < T1){
      int o = e / 160, c = e % 160;
      float v = 0.f;
      if (c < 128) v = w1[o*131 + 3 + c];
      else if (c < 131) v = w1[o*131 + (c - 128)];
      W1b[e] = f2b(v);
    } else if (e < T1+T2){
      int e2 = e - T1;
      W2b[e2] = f2b(w2[e2]);
    } else {
      int e3 = e - T1 - T2;
      W3b[e3] = f2b(w3[e3]);
    }
  }
}

// ---------------- conv1: gather (feat|xyzdiff) -> GEMM, W in registers ------
// waves split columns: wave wv owns cols [wv*32, wv*32+32)
__global__ __launch_bounds__(256, 2) void conv1_k(
    const float* __restrict__ xyz, const ushort_t* __restrict__ ftr_t,
    const int* __restrict__ idx, const float* __restrict__ new_xyz,
    const ushort_t* __restrict__ W1b, const float* __restrict__ b1,
    ushort_t* __restrict__ Y1, float* __restrict__ sumO, float* __restrict__ sqO)
{
  __shared__ alignas(16) ushort_t Xs[32*168];
  __shared__ alignas(16) float Ys[32*132];
  int t = threadIdx.x;
  int wv = t >> 6, lane = t & 63, quad = lane >> 4, l15 = lane & 15;
  int row = t >> 3, chunk = t & 7;

  // zero pad cols 128..159 once (col 131..159 stay zero; 128..131 rewritten/group)
  if (t < 128){
    int rr = t >> 2, cc = t & 3;
    *(uint4*)(Xs + rr*168 + 128 + cc*8) = make_uint4(0,0,0,0);
  }
  // W fragments in registers: 2 n-tiles x 5 k-tiles
  bf16x8 wf[2][5];
  #pragma unroll
  for (int nt = 0; nt < 2; nt++)
    #pragma unroll
    for (int kt = 0; kt < 5; kt++)
      wf[nt][kt] = *(const bf16x8*)(W1b + (wv*32 + nt*16 + l15)*160 + kt*32 + quad*8);
  float bs_r[2] = { b1[wv*32 + l15], b1[wv*32 + 16 + l15] };
  float s[2] = {0.f,0.f}, s2[2] = {0.f,0.f};

  const int GPB = 8;
  int g0 = blockIdx.x * GPB;
  for (int i = 0; i < GPB; i++){
    int g = g0 + i;
    int b = g >> 10;
    // gather staging: 8 threads/row, 32B each (contiguous per row)
    int n = idx[g*K_ + row];
    const ushort_t* src = ftr_t + ((size_t)b*N_ + n)*C_ + chunk*16;
    uint4 q0 = *(const uint4*)src;
    uint4 q1 = *(const uint4*)(src + 8);
    *(uint4*)(Xs + row*168 + chunk*16) = q0;
    *(uint4*)(Xs + row*168 + chunk*16 + 8) = q1;
    if (t < 32){
      int n2 = idx[g*K_ + t];
      const float* pp = xyz + ((size_t)b*N_ + n2)*3;
      const float* qq = new_xyz + (size_t)g*3;
      unsigned int u0 = (unsigned int)f2b(pp[0]-qq[0]) | ((unsigned int)f2b(pp[1]-qq[1]) << 16);
      unsigned int u1 = (unsigned int)f2b(pp[2]-qq[2]);
      *(uint2*)(Xs + t*168 + 128) = make_uint2(u0, u1);
    }
    __syncthreads();
    bf16x8 af[2][5];
    #pragma unroll
    for (int mt = 0; mt < 2; mt++)
      #pragma unroll
      for (int kt = 0; kt < 5; kt++)
        af[mt][kt] = *(const bf16x8*)(Xs + (mt*16 + l15)*168 + kt*32 + quad*8);
    f32x4 acc[2][2];
    #pragma unroll
    for (int nt = 0; nt < 2; nt++){ acc[nt][0] = (f32x4){0,0,0,0}; acc[nt][1] = (f32x4){0,0,0,0}; }
    #pragma unroll
    for (int nt = 0; nt < 2; nt++)
      #pragma unroll
      for (int kt = 0; kt < 5; kt++){
        acc[nt][0] = __builtin_amdgcn_mfma_f32_16x16x32_bf16(af[0][kt], wf[nt][kt], acc[nt][0], 0,0,0);
        acc[nt][1] = __builtin_amdgcn_mfma_f32_16x16x32_bf16(af[1][kt], wf[nt][kt], acc[nt][1], 0,0,0);
      }
    // epilogue: bias + stats + LDS transpose
    #pragma unroll
    for (int nt = 0; nt < 2; nt++){
      int o = wv*32 + nt*16 + l15;
      #pragma unroll
      for (int mt = 0; mt < 2; mt++)
        #pragma unroll
        for (int r = 0; r < 4; r++){
          float v = acc[nt][mt][r] + bs_r[nt];
          s[nt] += v; s2[nt] += v*v;
          Ys[(mt*16 + quad*4 + r)*132 + o] = v;
        }
    }
    __syncthreads();
    // readback: 64B (16 f32) per thread -> bf16 -> coalesced 32B store
    {
      const float* yp = &Ys[row*132 + chunk*16];
      f32x4 y0 = *(const f32x4*)(yp);
      f32x4 y1 = *(const f32x4*)(yp + 4);
      f32x4 y2 = *(const f32x4*)(yp + 8);
      f32x4 y3 = *(const f32x4*)(yp + 12);
      union { ushort_t u[8]; uint4 q; } p0, p1;
      #pragma unroll
      for (int j = 0; j < 4; j++){
        p0.u[j] = f2b(y0[j]); p0.u[4+j] = f2b(y1[j]);
        p1.u[j] = f2b(y2[j]); p1.u[4+j] = f2b(y3[j]);
      }
      ushort_t* dst = Y1 + ((size_t)g*K_ + row)*128 + chunk*16;
      *(uint4*)dst = p0.q;
      *(uint4*)(dst + 8) = p1.q;
    }
  }
  // stats: reduce quads, one atomic per column per block
  #pragma unroll
  for (int nt = 0; nt < 2; nt++){
    s[nt]  += __shfl_xor(s[nt], 16);  s[nt]  += __shfl_xor(s[nt], 32);
    s2[nt] += __shfl_xor(s2[nt], 16); s2[nt] += __shfl_xor(s2[nt], 32);
    if (quad == 0){
      int o = wv*32 + nt*16 + l15;
      atomicAdd(&sumO[o], s[nt]);
      atomicAdd(&sqO[o], s2[nt]);
    }
  }
}

// ---------------- conv2/conv3: BN(prev)+relu staging, W in registers --------
// MAXMIN=true (conv3): fuse max/min over K, emit packed bf16 pair, no Y write.
template<int COUT, bool MAXMIN>
__global__ __launch_bounds__(256, 2) void convB_k(
    const ushort_t* __restrict__ Yin, const ushort_t* __restrict__ Wb,
    const float* __restrict__ bias, const float* __restrict__ g_bn,
    const float* __restrict__ beta_bn, const float* __restrict__ sumI,
    const float* __restrict__ sqI, ushort_t* __restrict__ Yout,
    unsigned int* __restrict__ Ymm, float* __restrict__ sumO, float* __restrict__ sqO)
{
  constexpr int NT = COUT/64;
  __shared__ alignas(16) ushort_t Xs[32*136];
  __shared__ alignas(16) float Ys[MAXMIN ? 4 : 32*132];
  int t = threadIdx.x;
  int wv = t >> 6, lane = t & 63, quad = lane >> 4, l15 = lane & 15;
  int row = t >> 3, chunk = t & 7;

  // per-thread BN coefficients for its 16 staging channels (fixed across groups)
  float a_r[16], d_r[16];
  #pragma unroll
  for (int j = 0; j < 16; j++){
    int c = chunk*16 + j;
    float mu  = sumI[c] * (1.f/NTOT);
    float var = sqI[c]  * (1.f/NTOT) - mu*mu;
    float a = g_bn[c] * rsqrtf(var + EPS_);
    a_r[j] = a; d_r[j] = beta_bn[c] - a*mu;
  }
  // W fragments in registers
  bf16x8 wf[NT][4];
  #pragma unroll
  for (int nt = 0; nt < NT; nt++)
    #pragma unroll
    for (int kt = 0; kt < 4; kt++)
      wf[nt][kt] = *(const bf16x8*)(Wb + (wv*(NT*16) + nt*16 + l15)*128 + kt*32 + quad*8);
  float bs_r[NT];
  #pragma unroll
  for (int nt = 0; nt < NT; nt++) bs_r[nt] = bias[wv*(NT*16) + nt*16 + l15];
  float s[NT], s2[NT];
  #pragma unroll
  for (int nt = 0; nt < NT; nt++){ s[nt] = 0.f; s2[nt] = 0.f; }

  const int GPB = 8;
  int g0 = blockIdx.x * GPB;
  uint4 r0, r1;
  {
    const ushort_t* src = Yin + ((size_t)g0*K_ + row)*128 + chunk*16;
    r0 = *(const uint4*)src; r1 = *(const uint4*)(src + 8);
  }
  for (int i = 0; i < GPB; i++){
    int g = g0 + i;
    // BN + relu + write Xs
    union { ushort_t u[8]; uint4 q; } i0, i1, o0, o1;
    i0.q = r0; i1.q = r1;
    #pragma unroll
    for (int j = 0; j < 8; j++){
      o0.u[j] = f2b(fmaxf(a_r[j]  *b2f(i0.u[j]) + d_r[j],   0.f));
      o1.u[j] = f2b(fmaxf(a_r[8+j]*b2f(i1.u[j]) + d_r[8+j], 0.f));
    }
    *(uint4*)(Xs + row*136 + chunk*16) = o0.q;
    *(uint4*)(Xs + row*136 + chunk*16 + 8) = o1.q;
    if (i + 1 < GPB){                  // prefetch next tile
      const ushort_t* src = Yin + ((size_t)(g+1)*K_ + row)*128 + chunk*16;
      r0 = *(const uint4*)src; r1 = *(const uint4*)(src + 8);
    }
    __syncthreads();
    bf16x8 af[2][4];
    #pragma unroll
    for (int mt = 0; mt < 2; mt++)
      #pragma unroll
      for (int kt = 0; kt < 4; kt++)
        af[mt][kt] = *(const bf16x8*)(Xs + (mt*16 + l15)*136 + kt*32 + quad*8);
    f32x4 acc[NT][2];
    #pragma unroll
    for (int nt = 0; nt < NT; nt++){ acc[nt][0] = (f32x4){0,0,0,0}; acc[nt][1] = (f32x4){0,0,0,0}; }
    #pragma unroll
    for (int nt = 0; nt < NT; nt++)
      #pragma unroll
      for (int kt = 0; kt < 4; kt++){
        acc[nt][0] = __builtin_amdgcn_mfma_f32_16x16x32_bf16(af[0][kt], wf[nt][kt], acc[nt][0], 0,0,0);
        acc[nt][1] = __builtin_amdgcn_mfma_f32_16x16x32_bf16(af[1][kt], wf[nt][kt], acc[nt][1], 0,0,0);
      }
    if constexpr (!MAXMIN){
      #pragma unroll
      for (int nt = 0; nt < NT; nt++){
        int o = wv*(NT*16) + nt*16 + l15;
        #pragma unroll
        for (int mt = 0; mt < 2; mt++)
          #pragma unroll
          for (int r = 0; r < 4; r++){
            float v = acc[nt][mt][r] + bs_r[nt];
            s[nt] += v; s2[nt] += v*v;
            Ys[(mt*16 + quad*4 + r)*132 + o] = v;
          }
      }
      __syncthreads();
      const float* yp = &Ys[row*132 + chunk*16];
      f32x4 y0 = *(const f32x4*)(yp);
      f32x4 y1 = *(const f32x4*)(yp + 4);
      f32x4 y2 = *(const f32x4*)(yp + 8);
      f32x4 y3 = *(const f32x4*)(yp + 12);
      union { ushort_t u[8]; uint4 q; } p0, p1;
      #pragma unroll
      for (int j = 0; j < 4; j++){
        p0.u[j] = f2b(y0[j]); p0.u[4+j] = f2b(y1[j]);
        p1.u[j] = f2b(y2[j]); p1.u[4+j] = f2b(y3[j]);
      }
      ushort_t* dst = Yout + ((size_t)g*K_ + row)*128 + chunk*16;
      *(uint4*)dst = p0.q;
      *(uint4*)(dst + 8) = p1.q;
    } else {
      #pragma unroll
      for (int nt = 0; nt < NT; nt++){
        float v0 = acc[nt][0][0] + bs_r[nt];
        float mx = v0, mn = v0;
        s[nt] += v0; s2[nt] += v0*v0;
        #pragma unroll
        for (int mt = 0; mt < 2; mt++)
          #pragma unroll
          for (int r = 0; r < 4; r++){
            if (mt == 0 && r == 0) continue;
            float v = acc[nt][mt][r] + bs_r[nt];
            s[nt] += v; s2[nt] += v*v;
            mx = fmaxf(mx, v); mn = fminf(mn, v);
          }
        mx = fmaxf(mx, __shfl_xor(mx, 16)); mx = fmaxf(mx, __shfl_xor(mx, 32));
        mn = fminf(mn, __shfl_xor(mn, 16)); mn = fminf(mn, __shfl_xor(mn, 32));
        if (quad == 0){
          int o = wv*64 + nt*16 + l15;
          Ymm[(size_t)g*256 + o] = (unsigned int)f2b(mx) | ((unsigned int)f2b(mn) << 16);
        }
      }
      __syncthreads();
    }
  }
  #pragma unroll
  for (int nt = 0; nt < NT; nt++){
    s[nt]  += __shfl_xor(s[nt], 16);  s[nt]  += __shfl_xor(s[nt], 32);
    s2[nt] += __shfl_xor(s2[nt], 16); s2[nt] += __shfl_xor(s2[nt], 32);
    if (quad == 0){
      int o = wv*(NT*16) + nt*16 + l15;
      atomicAdd(&sumO[o], s[nt]);
      atomicAdd(&sqO[o], s2[nt]);
    }
  }
}

// ---------------- finalize: BN3 from max/min pairs, transposed store --------
__global__ __launch_bounds__(256) void finalize_k(
    const unsigned int* __restrict__ Ymm, const float* __restrict__ g3,
    const float* __restrict__ beta3, const float* __restrict__ sum3,
    const float* __restrict__ sq3, float* __restrict__ out)
{
  __shared__ float T[16][264];
  __shared__ float abn[256], dbn[256];
  int t = threadIdx.x;
  int b = blockIdx.x >> 6;
  int m0 = (blockIdx.x & 63) * 16;
  {
    float mu  = sum3[t] * (1.f/NTOT);
    float var = sq3[t]  * (1.f/NTOT) - mu*mu;
    float a = g3[t] * rsqrtf(var + EPS_);
    abn[t] = a; dbn[t] = beta3[t] - a*mu;
  }
  __syncthreads();
  #pragma unroll
  for (int i = 0; i < 4; i++){
    int v4 = i*256 + t;
    int m = v4 >> 6, oq = (v4 & 63) * 4;
    uint4 w = *(const uint4*)(Ymm + ((size_t)(b*M_ + m0 + m))*256 + oq);
    unsigned int wsv[4] = {w.x, w.y, w.z, w.w};
    float r[4];
    #pragma unroll
    for (int j = 0; j < 4; j++){
      int o = oq + j;
      float mx = b2f((ushort_t)(wsv[j] & 0xffffu));
      float mn = b2f((ushort_t)(wsv[j] >> 16));
      float a = abn[o];
      float val = (a >= 0.f) ? (a*mx + dbn[o]) : (a*mn + dbn[o]);
      r[j] = fmaxf(val, 0.f);
    }
    *(f32x4*)(&T[m][oq]) = *(f32x4*)r;
  }
  __syncthreads();
  #pragma unroll
  for (int p = 0; p < 4; p++){
    int o = p*64 + (t >> 2), c = t & 3;
    float4 v = make_float4(T[c*4+0][o], T[c*4+1][o], T[c*4+2][o], T[c*4+3][o]);
    *(float4*)(out + ((size_t)(b*256 + o))*M_ + m0 + c*4) = v;
  }
}

extern "C" void kernel_launch(void* const* d_in, const int* in_sizes, int n_in,
                              void* d_out, int out_size, void* d_ws, size_t ws_size,
                              hipStream_t stream)
{
  (void)in_sizes; (void)n_in; (void)out_size; (void)ws_size;
  const float* xyz  = (const float*)d_in[0];
  const float* feat = (const float*)d_in[1];
  const int*   inds = (const int*)d_in[2];
  const float* w1 = (const float*)d_in[3];
  const float* b1 = (const float*)d_in[4];
  const float* g1 = (const float*)d_in[5];
  const float* be1= (const float*)d_in[6];
  const float* w2 = (const float*)d_in[7];
  const float* b2 = (const float*)d_in[8];
  const float* g2 = (const float*)d_in[9];
  const float* be2= (const float*)d_in[10];
  const float* w3 = (const float*)d_in[11];
  const float* b3 = (const float*)d_in[12];
  const float* g3 = (const float*)d_in[13];
  const float* be3= (const float*)d_in[14];

  char* ws = (char*)d_ws;
  float* stats = (float*)ws;
  float* s1sum = stats + 0*256;  float* s1sq = stats + 1*256;
  float* s2sum = stats + 2*256;  float* s2sq = stats + 3*256;
  float* s3sum = stats + 4*256;  float* s3sq = stats + 5*256;
  size_t off = 6*256*sizeof(float);
  int* idx = (int*)(ws + off);                off += (size_t)B_*M_*K_*4;
  ushort_t* ftr_t = (ushort_t*)(ws + off);    off += (size_t)B_*N_*C_*2;
  ushort_t* W1b = (ushort_t*)(ws + off);      off += 128*160*2;
  ushort_t* W2b = (ushort_t*)(ws + off);      off += 128*128*2;
  ushort_t* W3b = (ushort_t*)(ws + off);      off += 256*128*2;
  ushort_t* Y1 = (ushort_t*)(ws + off);       off += (size_t)NTOT*128*2;
  ushort_t* Y2 = (ushort_t*)(ws + off);       off += (size_t)NTOT*128*2;
  unsigned int* Ymm = (unsigned int*)(ws + off); off += (size_t)B_*M_*256*4;

  float* new_xyz  = (float*)d_out;
  float* out_feat = (float*)d_out + (size_t)B_*M_*3;

  hipMemsetAsync(stats, 0, 6*256*sizeof(float), stream);
  prep_w_k<<<272, 256, 0, stream>>>(w1, w2, w3, W1b, W2b, W3b);
  transpose_feat_k<<<2048, 256, 0, stream>>>(feat, ftr_t);
  ball_query_k<<<1024, 256, 0, stream>>>(xyz, inds, new_xyz, idx);
  conv1_k<<<512, 256, 0, stream>>>(xyz, ftr_t, idx, new_xyz, W1b, b1, Y1, s1sum, s1sq);
  convB_k<128,false><<<512, 256, 0, stream>>>(Y1, W2b, b2, g1, be1, s1sum, s1sq, Y2, nullptr, s2sum, s2sq);
  convB_k<256,true ><<<512, 256, 0, stream>>>(Y2, W3b, b3, g2, be2, s2sum, s2sq, nullptr, Ymm, s3sum, s3sq);
  finalize_k<<<256, 256, 0, stream>>>(Ymm, g3, be3, s3sum, s3sq, out_feat);
}

// Round 4
// 227.641 us; speedup vs baseline: 1.5663x; 1.0991x over previous
//
#include <hip/hip_runtime.h>

#define B_ 4
#define N_ 16384
#define C_ 128
#define M_ 1024
#define K_ 32
#define NTOT (B_*M_*K_)   /* 131072 */
#define RAD2 0.16f
#define EPS_ 1e-5f

typedef unsigned short ushort_t;
typedef __bf16 bf16x8 __attribute__((ext_vector_type(8)));
typedef float f32x4 __attribute__((ext_vector_type(4)));

__device__ __forceinline__ float b2f(ushort_t u){
  unsigned int x = ((unsigned int)u) << 16;
  return __builtin_bit_cast(float, x);
}
__device__ __forceinline__ ushort_t f2b(float f){
  unsigned int u = __builtin_bit_cast(unsigned int, f);
  unsigned int r = (u + 0x7FFFu + ((u >> 16) & 1u)) >> 16;
  return (ushort_t)r;
}

// ---------------- ball query: 1 wave per query, no LDS, no barriers ---------
// Lane owns 8 consecutive points per 512-pt chunk (6 x dwordx4, coalesced),
// register double-buffered. Hit mask -> wave prefix sum -> ordered slots.
// Waves exit independently: no block coupling, stragglers don't stall others.
__global__ __launch_bounds__(256) void ball_query_k(
    const float* __restrict__ xyz, const int* __restrict__ indices,
    float* __restrict__ new_xyz, int* __restrict__ idx)
{
  int t = threadIdx.x;
  int wv = t >> 6, lane = t & 63;
  int g = blockIdx.x*4 + wv;
  int b = g >> 10;
  const float* pb = xyz + (size_t)b*N_*3;
  const float4* pb4 = (const float4*)pb;
  int qi = indices[g];
  float qx = pb[qi*3+0], qy = pb[qi*3+1], qz = pb[qi*3+2];
  if (lane < 3) new_xyz[g*3 + lane] = pb[qi*3 + lane];

  int cnt = 0, firstIdx = 0;
  int* op = idx + g*K_;

  float4 buf0[6], buf1[6];
  #pragma unroll
  for (int i = 0; i < 6; i++) buf0[i] = pb4[lane*6 + i];

  auto process = [&](const float4* buf, int chunk){
    const float* f = (const float*)buf;
    unsigned int local_mask = 0;
    #pragma unroll
    for (int j = 0; j < 8; j++){
      float dx = f[j*3+0]-qx, dy = f[j*3+1]-qy, dz = f[j*3+2]-qz;
      if (dx*dx + dy*dy + dz*dz < RAD2) local_mask |= (1u << j);
    }
    if (__ballot(local_mask != 0) == 0ull) return;   // fast skip: no hits
    int base = chunk*512;
    int lcnt = __popc(local_mask);
    int incl = lcnt;
    #pragma unroll
    for (int d = 1; d < 64; d <<= 1){
      int tt = __shfl_up(incl, d);
      if (lane >= d) incl += tt;
    }
    int excl = incl - lcnt;
    int total = __shfl(incl, 63);
    if (cnt == 0){                                   // first hit anywhere
      int lf = local_mask ? (lane*8 + __builtin_ctz(local_mask)) : 0x7fffffff;
      #pragma unroll
      for (int d = 1; d < 64; d <<= 1) lf = min(lf, __shfl_xor(lf, d));
      firstIdx = base + lf;
    }
    int sl = cnt + excl;
    unsigned int m = local_mask;
    while (m && sl < K_){
      int j = __builtin_ctz(m); m &= m - 1u;
      op[sl++] = base + lane*8 + j;
    }
    cnt += total;
  };

  for (int chunk = 0; chunk < 32; chunk += 2){
    if (chunk + 1 < 32){
      #pragma unroll
      for (int i = 0; i < 6; i++) buf1[i] = pb4[(chunk+1)*384 + lane*6 + i];
    }
    process(buf0, chunk);
    if (cnt >= K_) break;
    if (chunk + 2 < 32){
      #pragma unroll
      for (int i = 0; i < 6; i++) buf0[i] = pb4[(chunk+2)*384 + lane*6 + i];
    }
    process(buf1, chunk + 1);
    if (cnt >= K_) break;
  }
  if (cnt < K_){
    for (int s = cnt + lane; s < K_; s += 64) op[s] = firstIdx;
  }
}

// ---------------- features (B,C,N) f32 -> (B,N,C) bf16 ----------------------
__global__ __launch_bounds__(256) void transpose_feat_k(
    const float* __restrict__ feat, ushort_t* __restrict__ ftr_t)
{
  __shared__ float T[32][133];
  int bi = blockIdx.x;
  int b = bi >> 9, ntile = bi & 511;
  int n0 = ntile * 32;
  int t = threadIdx.x;
  int nl = t & 31;
  #pragma unroll
  for (int ci = 0; ci < 16; ci++){
    int c = ci*8 + (t >> 5);
    T[nl][c] = feat[((size_t)b*C_ + c)*N_ + n0 + nl];
  }
  __syncthreads();
  #pragma unroll
  for (int ii = 0; ii < 2; ii++){
    int v = ii*256 + t;
    int n2 = v >> 4, seg = v & 15;
    union { ushort_t u[8]; uint4 q; } pk;
    #pragma unroll
    for (int j = 0; j < 8; j++) pk.u[j] = f2b(T[n2][seg*8 + j]);
    *(uint4*)(ftr_t + ((size_t)b*N_ + n0 + n2)*C_ + seg*8) = pk.q;
  }
}

// ---------------- weights f32 -> bf16 (W1 reordered: feat|xyz|0, stride 160) -
__global__ __launch_bounds__(256) void prep_w_k(
    const float* __restrict__ w1, const float* __restrict__ w2, const float* __restrict__ w3,
    ushort_t* __restrict__ W1b, ushort_t* __restrict__ W2b, ushort_t* __restrict__ W3b)
{
  const int T1 = 128*160, T2 = 128*128, T3 = 256*128;
  for (int e = blockIdx.x*256 + threadIdx.x; e < T1+T2+T3; e += gridDim.x*256){
    if (e < T1){
      int o = e / 160, c = e % 160;
      float v = 0.f;
      if (c < 128) v = w1[o*131 + 3 + c];
      else if (c < 131) v = w1[o*131 + (c - 128)];
      W1b[e] = f2b(v);
    } else if (e < T1+T2){
      int e2 = e - T1;
      W2b[e2] = f2b(w2[e2]);
    } else {
      int e3 = e - T1 - T2;
      W3b[e3] = f2b(w3[e3]);
    }
  }
}

// ---------------- conv1: gather (feat|xyzdiff) -> GEMM, W in registers ------
__global__ __launch_bounds__(256, 2) void conv1_k(
    const float* __restrict__ xyz, const ushort_t* __restrict__ ftr_t,
    const int* __restrict__ idx, const float* __restrict__ new_xyz,
    const ushort_t* __restrict__ W1b, const float* __restrict__ b1,
    ushort_t* __restrict__ Y1, float* __restrict__ sumO, float* __restrict__ sqO)
{
  __shared__ alignas(16) ushort_t Xs[32*168];
  __shared__ alignas(16) float Ys[32*132];
  int t = threadIdx.x;
  int wv = t >> 6, lane = t & 63, quad = lane >> 4, l15 = lane & 15;
  int row = t >> 3, chunk = t & 7;

  if (t < 128){
    int rr = t >> 2, cc = t & 3;
    *(uint4*)(Xs + rr*168 + 128 + cc*8) = make_uint4(0,0,0,0);
  }
  bf16x8 wf[2][5];
  #pragma unroll
  for (int nt = 0; nt < 2; nt++)
    #pragma unroll
    for (int kt = 0; kt < 5; kt++)
      wf[nt][kt] = *(const bf16x8*)(W1b + (wv*32 + nt*16 + l15)*160 + kt*32 + quad*8);
  float bs_r[2] = { b1[wv*32 + l15], b1[wv*32 + 16 + l15] };
  float s[2] = {0.f,0.f}, s2[2] = {0.f,0.f};

  const int GPB = 8;
  int g0 = blockIdx.x * GPB;
  for (int i = 0; i < GPB; i++){
    int g = g0 + i;
    int b = g >> 10;
    int n = idx[g*K_ + row];
    const ushort_t* src = ftr_t + ((size_t)b*N_ + n)*C_ + chunk*16;
    uint4 q0 = *(const uint4*)src;
    uint4 q1 = *(const uint4*)(src + 8);
    *(uint4*)(Xs + row*168 + chunk*16) = q0;
    *(uint4*)(Xs + row*168 + chunk*16 + 8) = q1;
    if (t < 32){
      int n2 = idx[g*K_ + t];
      const float* pp = xyz + ((size_t)b*N_ + n2)*3;
      const float* qq = new_xyz + (size_t)g*3;
      unsigned int u0 = (unsigned int)f2b(pp[0]-qq[0]) | ((unsigned int)f2b(pp[1]-qq[1]) << 16);
      unsigned int u1 = (unsigned int)f2b(pp[2]-qq[2]);
      *(uint2*)(Xs + t*168 + 128) = make_uint2(u0, u1);
    }
    __syncthreads();
    bf16x8 af[2][5];
    #pragma unroll
    for (int mt = 0; mt < 2; mt++)
      #pragma unroll
      for (int kt = 0; kt < 5; kt++)
        af[mt][kt] = *(const bf16x8*)(Xs + (mt*16 + l15)*168 + kt*32 + quad*8);
    f32x4 acc[2][2];
    #pragma unroll
    for (int nt = 0; nt < 2; nt++){ acc[nt][0] = (f32x4){0,0,0,0}; acc[nt][1] = (f32x4){0,0,0,0}; }
    #pragma unroll
    for (int nt = 0; nt < 2; nt++)
      #pragma unroll
      for (int kt = 0; kt < 5; kt++){
        acc[nt][0] = __builtin_amdgcn_mfma_f32_16x16x32_bf16(af[0][kt], wf[nt][kt], acc[nt][0], 0,0,0);
        acc[nt][1] = __builtin_amdgcn_mfma_f32_16x16x32_bf16(af[1][kt], wf[nt][kt], acc[nt][1], 0,0,0);
      }
    #pragma unroll
    for (int nt = 0; nt < 2; nt++){
      int o = wv*32 + nt*16 + l15;
      #pragma unroll
      for (int mt = 0; mt < 2; mt++)
        #pragma unroll
        for (int r = 0; r < 4; r++){
          float v = acc[nt][mt][r] + bs_r[nt];
          s[nt] += v; s2[nt] += v*v;
          Ys[(mt*16 + quad*4 + r)*132 + o] = v;
        }
    }
    __syncthreads();
    {
      const float* yp = &Ys[row*132 + chunk*16];
      f32x4 y0 = *(const f32x4*)(yp);
      f32x4 y1 = *(const f32x4*)(yp + 4);
      f32x4 y2 = *(const f32x4*)(yp + 8);
      f32x4 y3 = *(const f32x4*)(yp + 12);
      union { ushort_t u[8]; uint4 q; } p0, p1;
      #pragma unroll
      for (int j = 0; j < 4; j++){
        p0.u[j] = f2b(y0[j]); p0.u[4+j] = f2b(y1[j]);
        p1.u[j] = f2b(y2[j]); p1.u[4+j] = f2b(y3[j]);
      }
      ushort_t* dst = Y1 + ((size_t)g*K_ + row)*128 + chunk*16;
      *(uint4*)dst = p0.q;
      *(uint4*)(dst + 8) = p1.q;
    }
  }
  #pragma unroll
  for (int nt = 0; nt < 2; nt++){
    s[nt]  += __shfl_xor(s[nt], 16);  s[nt]  += __shfl_xor(s[nt], 32);
    s2[nt] += __shfl_xor(s2[nt], 16); s2[nt] += __shfl_xor(s2[nt], 32);
    if (quad == 0){
      int o = wv*32 + nt*16 + l15;
      atomicAdd(&sumO[o], s[nt]);
      atomicAdd(&sqO[o], s2[nt]);
    }
  }
}

// ---------------- conv2/conv3: BN(prev)+relu staging, W in registers --------
template<int COUT, bool MAXMIN>
__global__ __launch_bounds__(256, 2) void convB_k(
    const ushort_t* __restrict__ Yin, const ushort_t* __restrict__ Wb,
    const float* __restrict__ bias, const float* __restrict__ g_bn,
    const float* __restrict__ beta_bn, const float* __restrict__ sumI,
    const float* __restrict__ sqI, ushort_t* __restrict__ Yout,
    unsigned int* __restrict__ Ymm, float* __restrict__ sumO, float* __restrict__ sqO)
{
  constexpr int NT = COUT/64;
  __shared__ alignas(16) ushort_t Xs[32*136];
  __shared__ alignas(16) float Ys[MAXMIN ? 4 : 32*132];
  int t = threadIdx.x;
  int wv = t >> 6, lane = t & 63, quad = lane >> 4, l15 = lane & 15;
  int row = t >> 3, chunk = t & 7;

  float a_r[16], d_r[16];
  #pragma unroll
  for (int j = 0; j < 16; j++){
    int c = chunk*16 + j;
    float mu  = sumI[c] * (1.f/NTOT);
    float var = sqI[c]  * (1.f/NTOT) - mu*mu;
    float a = g_bn[c] * rsqrtf(var + EPS_);
    a_r[j] = a; d_r[j] = beta_bn[c] - a*mu;
  }
  bf16x8 wf[NT][4];
  #pragma unroll
  for (int nt = 0; nt < NT; nt++)
    #pragma unroll
    for (int kt = 0; kt < 4; kt++)
      wf[nt][kt] = *(const bf16x8*)(Wb + (wv*(NT*16) + nt*16 + l15)*128 + kt*32 + quad*8);
  float bs_r[NT];
  #pragma unroll
  for (int nt = 0; nt < NT; nt++) bs_r[nt] = bias[wv*(NT*16) + nt*16 + l15];
  float s[NT], s2[NT];
  #pragma unroll
  for (int nt = 0; nt < NT; nt++){ s[nt] = 0.f; s2[nt] = 0.f; }

  const int GPB = 8;
  int g0 = blockIdx.x * GPB;
  uint4 r0, r1;
  {
    const ushort_t* src = Yin + ((size_t)g0*K_ + row)*128 + chunk*16;
    r0 = *(const uint4*)src; r1 = *(const uint4*)(src + 8);
  }
  for (int i = 0; i < GPB; i++){
    int g = g0 + i;
    union { ushort_t u[8]; uint4 q; } i0, i1, o0, o1;
    i0.q = r0; i1.q = r1;
    #pragma unroll
    for (int j = 0; j < 8; j++){
      o0.u[j] = f2b(fmaxf(a_r[j]  *b2f(i0.u[j]) + d_r[j],   0.f));
      o1.u[j] = f2b(fmaxf(a_r[8+j]*b2f(i1.u[j]) + d_r[8+j], 0.f));
    }
    *(uint4*)(Xs + row*136 + chunk*16) = o0.q;
    *(uint4*)(Xs + row*136 + chunk*16 + 8) = o1.q;
    if (i + 1 < GPB){
      const ushort_t* src = Yin + ((size_t)(g+1)*K_ + row)*128 + chunk*16;
      r0 = *(const uint4*)src; r1 = *(const uint4*)(src + 8);
    }
    __syncthreads();
    bf16x8 af[2][4];
    #pragma unroll
    for (int mt = 0; mt < 2; mt++)
      #pragma unroll
      for (int kt = 0; kt < 4; kt++)
        af[mt][kt] = *(const bf16x8*)(Xs + (mt*16 + l15)*136 + kt*32 + quad*8);
    f32x4 acc[NT][2];
    #pragma unroll
    for (int nt = 0; nt < NT; nt++){ acc[nt][0] = (f32x4){0,0,0,0}; acc[nt][1] = (f32x4){0,0,0,0}; }
    #pragma unroll
    for (int nt = 0; nt < NT; nt++)
      #pragma unroll
      for (int kt = 0; kt < 4; kt++){
        acc[nt][0] = __builtin_amdgcn_mfma_f32_16x16x32_bf16(af[0][kt], wf[nt][kt], acc[nt][0], 0,0,0);
        acc[nt][1] = __builtin_amdgcn_mfma_f32_16x16x32_bf16(af[1][kt], wf[nt][kt], acc[nt][1], 0,0,0);
      }
    if constexpr (!MAXMIN){
      #pragma unroll
      for (int nt = 0; nt < NT; nt++){
        int o = wv*(NT*16) + nt*16 + l15;
        #pragma unroll
        for (int mt = 0; mt < 2; mt++)
          #pragma unroll
          for (int r = 0; r < 4; r++){
            float v = acc[nt][mt][r] + bs_r[nt];
            s[nt] += v; s2[nt] += v*v;
            Ys[(mt*16 + quad*4 + r)*132 + o] = v;
          }
      }
      __syncthreads();
      const float* yp = &Ys[row*132 + chunk*16];
      f32x4 y0 = *(const f32x4*)(yp);
      f32x4 y1 = *(const f32x4*)(yp + 4);
      f32x4 y2 = *(const f32x4*)(yp + 8);
      f32x4 y3 = *(const f32x4*)(yp + 12);
      union { ushort_t u[8]; uint4 q; } p0, p1;
      #pragma unroll
      for (int j = 0; j < 4; j++){
        p0.u[j] = f2b(y0[j]); p0.u[4+j] = f2b(y1[j]);
        p1.u[j] = f2b(y2[j]); p1.u[4+j] = f2b(y3[j]);
      }
      ushort_t* dst = Yout + ((size_t)g*K_ + row)*128 + chunk*16;
      *(uint4*)dst = p0.q;
      *(uint4*)(dst + 8) = p1.q;
    } else {
      #pragma unroll
      for (int nt = 0; nt < NT; nt++){
        float v0 = acc[nt][0][0] + bs_r[nt];
        float mx = v0, mn = v0;
        s[nt] += v0; s2[nt] += v0*v0;
        #pragma unroll
        for (int mt = 0; mt < 2; mt++)
          #pragma unroll
          for (int r = 0; r < 4; r++){
            if (mt == 0 && r == 0) continue;
            float v = acc[nt][mt][r] + bs_r[nt];
            s[nt] += v; s2[nt] += v*v;
            mx = fmaxf(mx, v); mn = fminf(mn, v);
          }
        mx = fmaxf(mx, __shfl_xor(mx, 16)); mx = fmaxf(mx, __shfl_xor(mx, 32));
        mn = fminf(mn, __shfl_xor(mn, 16)); mn = fminf(mn, __shfl_xor(mn, 32));
        if (quad == 0){
          int o = wv*64 + nt*16 + l15;
          Ymm[(size_t)g*256 + o] = (unsigned int)f2b(mx) | ((unsigned int)f2b(mn) << 16);
        }
      }
      __syncthreads();
    }
  }
  #pragma unroll
  for (int nt = 0; nt < NT; nt++){
    s[nt]  += __shfl_xor(s[nt], 16);  s[nt]  += __shfl_xor(s[nt], 32);
    s2[nt] += __shfl_xor(s2[nt], 16); s2[nt] += __shfl_xor(s2[nt], 32);
    if (quad == 0){
      int o = wv*(NT*16) + nt*16 + l15;
      atomicAdd(&sumO[o], s[nt]);
      atomicAdd(&sqO[o], s2[nt]);
    }
  }
}

// ---------------- finalize: BN3 from max/min pairs, transposed store --------
__global__ __launch_bounds__(256) void finalize_k(
    const unsigned int* __restrict__ Ymm, const float* __restrict__ g3,
    const float* __restrict__ beta3, const float* __restrict__ sum3,
    const float* __restrict__ sq3, float* __restrict__ out)
{
  __shared__ float T[16][264];
  __shared__ float abn[256], dbn[256];
  int t = threadIdx.x;
  int b = blockIdx.x >> 6;
  int m0 = (blockIdx.x & 63) * 16;
  {
    float mu  = sum3[t] * (1.f/NTOT);
    float var = sq3[t]  * (1.f/NTOT) - mu*mu;
    float a = g3[t] * rsqrtf(var + EPS_);
    abn[t] = a; dbn[t] = beta3[t] - a*mu;
  }
  __syncthreads();
  #pragma unroll
  for (int i = 0; i < 4; i++){
    int v4 = i*256 + t;
    int m = v4 >> 6, oq = (v4 & 63) * 4;
    uint4 w = *(const uint4*)(Ymm + ((size_t)(b*M_ + m0 + m))*256 + oq);
    unsigned int wsv[4] = {w.x, w.y, w.z, w.w};
    float r[4];
    #pragma unroll
    for (int j = 0; j < 4; j++){
      int o = oq + j;
      float mx = b2f((ushort_t)(wsv[j] & 0xffffu));
      float mn = b2f((ushort_t)(wsv[j] >> 16));
      float a = abn[o];
      float val = (a >= 0.f) ? (a*mx + dbn[o]) : (a*mn + dbn[o]);
      r[j] = fmaxf(val, 0.f);
    }
    *(f32x4*)(&T[m][oq]) = *(f32x4*)r;
  }
  __syncthreads();
  #pragma unroll
  for (int p = 0; p < 4; p++){
    int o = p*64 + (t >> 2), c = t & 3;
    float4 v = make_float4(T[c*4+0][o], T[c*4+1][o], T[c*4+2][o], T[c*4+3][o]);
    *(float4*)(out + ((size_t)(b*256 + o))*M_ + m0 + c*4) = v;
  }
}

extern "C" void kernel_launch(void* const* d_in, const int* in_sizes, int n_in,
                              void* d_out, int out_size, void* d_ws, size_t ws_size,
                              hipStream_t stream)
{
  (void)in_sizes; (void)n_in; (void)out_size; (void)ws_size;
  const float* xyz  = (const float*)d_in[0];
  const float* feat = (const float*)d_in[1];
  const int*   inds = (const int*)d_in[2];
  const float* w1 = (const float*)d_in[3];
  const float* b1 = (const float*)d_in[4];
  const float* g1 = (const float*)d_in[5];
  const float* be1= (const float*)d_in[6];
  const float* w2 = (const float*)d_in[7];
  const float* b2 = (const float*)d_in[8];
  const float* g2 = (const float*)d_in[9];
  const float* be2= (const float*)d_in[10];
  const float* w3 = (const float*)d_in[11];
  const float* b3 = (const float*)d_in[12];
  const float* g3 = (const float*)d_in[13];
  const float* be3= (const float*)d_in[14];

  char* ws = (char*)d_ws;
  float* stats = (float*)ws;
  float* s1sum = stats + 0*256;  float* s1sq = stats + 1*256;
  float* s2sum = stats + 2*256;  float* s2sq = stats + 3*256;
  float* s3sum = stats + 4*256;  float* s3sq = stats + 5*256;
  size_t off = 6*256*sizeof(float);
  int* idx = (int*)(ws + off);                off += (size_t)B_*M_*K_*4;
  ushort_t* ftr_t = (ushort_t*)(ws + off);    off += (size_t)B_*N_*C_*2;
  ushort_t* W1b = (ushort_t*)(ws + off);      off += 128*160*2;
  ushort_t* W2b = (ushort_t*)(ws + off);      off += 128*128*2;
  ushort_t* W3b = (ushort_t*)(ws + off);      off += 256*128*2;
  ushort_t* Y1 = (ushort_t*)(ws + off);       off += (size_t)NTOT*128*2;
  ushort_t* Y2 = (ushort_t*)(ws + off);       off += (size_t)NTOT*128*2;
  unsigned int* Ymm = (unsigned int*)(ws + off); off += (size_t)B_*M_*256*4;

  float* new_xyz  = (float*)d_out;
  float* out_feat = (float*)d_out + (size_t)B_*M_*3;

  hipMemsetAsync(stats, 0, 6*256*sizeof(float), stream);
  prep_w_k<<<272, 256, 0, stream>>>(w1, w2, w3, W1b, W2b, W3b);
  transpose_feat_k<<<2048, 256, 0, stream>>>(feat, ftr_t);
  ball_query_k<<<1024, 256, 0, stream>>>(xyz, inds, new_xyz, idx);
  conv1_k<<<512, 256, 0, stream>>>(xyz, ftr_t, idx, new_xyz, W1b, b1, Y1, s1sum, s1sq);
  convB_k<128,false><<<512, 256, 0, stream>>>(Y1, W2b, b2, g1, be1, s1sum, s1sq, Y2, nullptr, s2sum, s2sq);
  convB_k<256,true ><<<512, 256, 0, stream>>>(Y2, W3b, b3, g2, be2, s2sum, s2sq, nullptr, Ymm, s3sum, s3sq);
  finalize_k<<<256, 256, 0, stream>>>(Ymm, g3, be3, s3sum, s3sq, out_feat);
}